// Round 2
// baseline (411.341 us; speedup 1.0000x reference)
//
#include <hip/hip_runtime.h>
#include <hip/hip_bf16.h>

#define D_MODEL 64
#define SEQ     4096
#define BATCH   256
#define NSIG    128

__device__ __forceinline__ float fast_rcp(float x) {
  return __builtin_amdgcn_rcpf(x);
}

constexpr float PHI_F     = 1.61803398874989484820f;
constexpr float TWO_PI_F  = 6.28318530717958647692f;
constexpr float INV2PI_F  = 0.15915494309189533577f;
constexpr float LUT_F     = 4096.0f;
constexpr float INV_LUT_F = 1.0f / 4096.0f;

// One block per batch element b; lane = model dim d (0..63).
// 4096-step serial scan; per-step coefficients (r2, c2) are prefetched and
// precomputed 8-16 steps ahead so only the h -> theta -> quantize -> sin/cos
// chain is on the critical path.
__global__ __launch_bounds__(64, 1)
void rin_scan_kernel(const int* __restrict__ ids,
                     const float* __restrict__ emb,   // (50257, 128) f32
                     const float* __restrict__ pw,    // (128, 128) f32
                     const float* __restrict__ pb,    // (128,) f32
                     float* __restrict__ out)         // (256, 128) f32
{
  __shared__ int   lds_ids[SEQ];
  __shared__ float lds_tp[SEQ];       // t_phi in revolutions: fmod(t*PHI, 2pi)/2pi
  __shared__ float lds_h[2 * D_MODEL];

  const int b    = blockIdx.x;
  const int lane = threadIdx.x;

  // ---- stage token ids for this batch row (coalesced int4) ----
  {
    const int4* src = (const int4*)(ids + b * SEQ);
    int4* dst = (int4*)lds_ids;
    #pragma unroll
    for (int i = 0; i < (SEQ / 4) / 64; ++i)
      dst[lane + i * 64] = src[lane + i * 64];
  }

  // ---- stage t_phi table (revolutions) ----
  #pragma unroll
  for (int i = 0; i < SEQ / 64; ++i) {
    int t = lane + i * 64;
    float pf = (float)t * PHI_F;
    float n  = floorf(pf * INV2PI_F);
    float tp = fmaf(-n, TWO_PI_F, pf);   // ~= fmodf(t*PHI, 2pi)
    lds_tp[t] = tp * INV2PI_F;
  }
  __syncthreads();

  float hr = 0.0f, hi = 0.0f;

  float w_n[8], b_n[8];        // raw f32 for steps [t0+8, t0+16)
  float r2[8], c2[8];          // ready coefficients for steps [t0, t0+8)

  auto load_raw = [&](int t0, float* wv, float* bv) {
    #pragma unroll
    for (int u = 0; u < 8; ++u) {
      int t = t0 + u; t = (t < SEQ) ? t : (SEQ - 1);
      int id = lds_ids[t];
      const float* row = emb + (long)id * (2 * D_MODEL);
      wv[u] = row[lane];
      bv[u] = row[D_MODEL + lane];
    }
  };

  auto compute_rc = [&](int t0, const float* wv, const float* bv,
                        float* r2o, float* c2o) {
    #pragma unroll
    for (int u = 0; u < 8; ++u) {
      int t = t0 + u; t = (t < SEQ) ? t : (SEQ - 1);
      float w  = wv[u];
      float bb = bv[u];
      float lam = 1.0f + fabsf(w);
      float r  = fast_rcp(lam);
      r2o[u] = r * INV2PI_F;
      c2o[u] = fmaf(bb, INV2PI_F, lds_tp[t]);
    }
  };

  // ---- pipeline prologue ----
  load_raw(0, w_n, b_n);
  compute_rc(0, w_n, b_n, r2, c2);
  load_raw(8, w_n, b_n);

  // ---- main scan ----
  for (int t0 = 0; t0 < SEQ; t0 += 8) {
    float w_f[8], b_f[8];
    load_raw(t0 + 16, w_f, b_f);                   // prefetch, independent
    float r2n[8], c2n[8];
    compute_rc(t0 + 8, w_n, b_n, r2n, c2n);        // independent of chain

    #pragma unroll
    for (int u = 0; u < 8; ++u) {
      // x = theta / 2pi  (revolutions)
      float xr = fmaf(hr, r2[u], c2[u]);
      float xi = fmaf(hi, r2[u], c2[u]);
      // quantize to LUT grid: k = floor(x*4096); angle = fract(k/4096)
      float zr = floorf(xr * LUT_F) * INV_LUT_F;
      float zi = floorf(xi * LUT_F) * INV_LUT_F;
      float fqr = zr - floorf(zr);    // in [0,1) -- valid v_sin/v_cos domain
      float fqi = zi - floorf(zi);
      float sr = __builtin_amdgcn_sinf(fqr);
      float cr = __builtin_amdgcn_cosf(fqr);
      float si = __builtin_amdgcn_sinf(fqi);
      float ci = __builtin_amdgcn_cosf(fqi);
      float t2 = sr * si;
      float t4 = sr * ci;
      hr = fmaf(cr, ci, -t2);      // cos(qr+qi)
      hi = fmaf(cr, si,  t4);      // sin(qr+qi)
    }

    #pragma unroll
    for (int u = 0; u < 8; ++u) {
      r2[u] = r2n[u]; c2[u] = c2n[u];
      w_n[u] = w_f[u]; b_n[u] = b_f[u];
    }
  }

  // ---- projection: out[b, j] = sum_k h_comb[k] * pw[j, k] + pb[j] ----
  __syncthreads();
  lds_h[lane] = hr;
  lds_h[D_MODEL + lane] = hi;
  __syncthreads();

  const int j0 = lane;
  const int j1 = lane + D_MODEL;
  const float* w0 = pw + j0 * NSIG;
  const float* w1 = pw + j1 * NSIG;
  float acc0 = 0.0f, acc1 = 0.0f;
  #pragma unroll 8
  for (int k = 0; k < NSIG; ++k) {
    float hk = lds_h[k];
    acc0 = fmaf(hk, w0[k], acc0);
    acc1 = fmaf(hk, w1[k], acc1);
  }
  acc0 += pb[j0];
  acc1 += pb[j1];

  out[b * NSIG + j0] = acc0;
  out[b * NSIG + j1] = acc1;
}

extern "C" void kernel_launch(void* const* d_in, const int* in_sizes, int n_in,
                              void* d_out, int out_size, void* d_ws, size_t ws_size,
                              hipStream_t stream) {
  const int*   ids = (const int*)d_in[0];
  const float* emb = (const float*)d_in[1];
  const float* pw  = (const float*)d_in[2];
  const float* pb  = (const float*)d_in[3];
  float*       out = (float*)d_out;

  rin_scan_kernel<<<dim3(BATCH), dim3(64), 0, stream>>>(ids, emb, pw, pb, out);
}

// Round 3
// 185.099 us; speedup vs baseline: 2.2223x; 2.2223x over previous
//
#include <hip/hip_runtime.h>

#define D_MODEL 64
#define SEQ     4096
#define BATCH   256
#define NSIG    128
#define CSTEP   64
#define NCHUNK  (SEQ / CSTEP)   // 64

constexpr float PHI_F     = 1.61803398874989484820f;
constexpr float TWO_PI_F  = 6.28318530717958647692f;
constexpr float INV2PI_F  = 0.15915494309189533577f;
constexpr float SCALE_F   = 4096.0f * 0.15915494309189533577f;  // 4096 / 2pi
constexpr float INV_LUT_F = 1.0f / 4096.0f;

// One block (256 threads = 4 waves) per batch element.
// wave 0: serial 4096-step scan (lane = model dim d).
// waves 1-3: loaders — gather emb rows, pre-transform into LUT-bin-scaled
// coefficients (r4 = 4096/2pi/lambda, c4 = (b + t*phi mod 2pi)*4096/2pi),
// stage into a double-buffered LDS ring one chunk (64 steps) ahead.
__global__ __launch_bounds__(256, 1)
void rin_scan_kernel(const int* __restrict__ ids,
                     const float* __restrict__ emb,   // (50257, 128) f32
                     const float* __restrict__ pw,    // (128, 128) f32
                     const float* __restrict__ pb,    // (128,) f32
                     float* __restrict__ out)         // (256, 128) f32
{
  __shared__ int   lds_ids[SEQ];                     // 16 KB
  __shared__ float lds_tp4[SEQ];                     // 16 KB: (t*PHI mod 2pi)*4096/2pi
  __shared__ float ring[2][CSTEP][2 * D_MODEL];      // 64 KB
  __shared__ float lds_h[2 * D_MODEL];

  const int tid  = threadIdx.x;
  const int wave = tid >> 6;
  const int lane = tid & 63;
  const int b    = blockIdx.x;

  // ---- stage token ids (coalesced int4, all 256 threads) ----
  {
    const int4* src = (const int4*)(ids + b * SEQ);
    int4* dst = (int4*)lds_ids;
    #pragma unroll
    for (int i = 0; i < SEQ / 4 / 256; ++i)          // 4 iters
      dst[tid + i * 256] = src[tid + i * 256];
  }
  // ---- stage t_phi table, pre-scaled to LUT bins ----
  #pragma unroll
  for (int i = 0; i < SEQ / 256; ++i) {              // 16 iters
    int t = tid + i * 256;
    float pf = (float)t * PHI_F;
    float n  = floorf(pf * INV2PI_F);
    float tp = fmaf(-n, TWO_PI_F, pf);               // fmod(t*PHI, 2pi)
    lds_tp4[t] = tp * SCALE_F;
  }
  __syncthreads();

  float hr = 0.0f, hi = 0.0f;

  // ---- loader: stage chunk c into ring slot s (waves 1-3 only) ----
  auto stage = [&](int c, int s) {
    // 32 step-pairs per chunk; wave w takes pairs p % 3 == w-1 (clamped dup ok)
    float4 v[11];
    int    st[11];
    #pragma unroll
    for (int k = 0; k < 11; ++k) {
      int p = (wave - 1) + 3 * k;
      p = (p < CSTEP / 2) ? p : (CSTEP / 2 - 1);     // clamp: duplicate write, same data
      int half = lane >> 5;                          // 0: step 2p, 1: step 2p+1
      int L    = lane & 31;                          // float4 index within row
      int i    = 2 * p + half;
      int t    = c * CSTEP + i;
      st[k] = i;
      int id = lds_ids[t];
      v[k] = ((const float4*)(emb + (size_t)id * (2 * D_MODEL)))[L];
    }
    #pragma unroll
    for (int k = 0; k < 11; ++k) {
      int i   = st[k];
      int t   = c * CSTEP + i;
      int L   = lane & 31;
      float tp4 = lds_tp4[t];
      float4 r;
      if (L < 16) {  // w columns 4L..4L+3  ->  r4 = SCALE / (1+|w|)
        r.x = __builtin_amdgcn_rcpf(1.0f + fabsf(v[k].x)) * SCALE_F;
        r.y = __builtin_amdgcn_rcpf(1.0f + fabsf(v[k].y)) * SCALE_F;
        r.z = __builtin_amdgcn_rcpf(1.0f + fabsf(v[k].z)) * SCALE_F;
        r.w = __builtin_amdgcn_rcpf(1.0f + fabsf(v[k].w)) * SCALE_F;
      } else {       // b columns -> c4 = b*SCALE + tp4
        r.x = fmaf(v[k].x, SCALE_F, tp4);
        r.y = fmaf(v[k].y, SCALE_F, tp4);
        r.z = fmaf(v[k].z, SCALE_F, tp4);
        r.w = fmaf(v[k].w, SCALE_F, tp4);
      }
      *(float4*)&ring[s][i][L * 4] = r;
    }
  };

  // ---- compute: consume one chunk from ring slot (wave 0 only) ----
  auto consume = [&](int slot) {
    const float* buf = &ring[slot][0][0];
    float r4c[8], c4c[8], r4n[8], c4n[8];
    #pragma unroll
    for (int u = 0; u < 8; ++u) {
      r4c[u] = buf[u * 128 + lane];
      c4c[u] = buf[u * 128 + 64 + lane];
    }
    for (int g = 0; g < CSTEP / 8; ++g) {
      if (g < CSTEP / 8 - 1) {
        #pragma unroll
        for (int u = 0; u < 8; ++u) {                // prefetch next group
          r4n[u] = buf[(g * 8 + 8 + u) * 128 + lane];
          c4n[u] = buf[(g * 8 + 8 + u) * 128 + 64 + lane];
        }
      }
      #pragma unroll
      for (int u = 0; u < 8; ++u) {
        float xr = fmaf(hr, r4c[u], c4c[u]);   // theta_r in LUT bins
        float xi = fmaf(hi, r4c[u], c4c[u]);
        float kr = floorf(xr);
        float ki = floorf(xi);
        float f  = (kr + ki) * INV_LUT_F;      // exact: int * 2^-12
        f = __builtin_amdgcn_fractf(f);        // mod 1 -> revolutions
        hr = __builtin_amdgcn_cosf(f);         // cos(qr+qi) = cr*ci - sr*si
        hi = __builtin_amdgcn_sinf(f);         // sin(qr+qi) = cr*si + sr*ci
      }
      #pragma unroll
      for (int u = 0; u < 8; ++u) { r4c[u] = r4n[u]; c4c[u] = c4n[u]; }
    }
  };

  // ---- pipeline: loaders stay 1 chunk ahead, barrier per chunk ----
  if (wave > 0) stage(0, 0);
  __syncthreads();
  for (int c = 0; c < NCHUNK; ++c) {
    if (wave > 0) {
      if (c + 1 < NCHUNK) stage(c + 1, (c + 1) & 1);
    } else {
      consume(c & 1);
    }
    __syncthreads();
  }

  // ---- projection: out[b, j] = sum_k h[k] * pw[j, k] + pb[j] ----
  if (wave == 0) {
    lds_h[lane] = hr;
    lds_h[D_MODEL + lane] = hi;
  }
  __syncthreads();
  if (tid < NSIG) {
    int j = tid;
    const float4* wrow = (const float4*)(pw + j * NSIG);
    float acc = pb[j];
    #pragma unroll
    for (int k = 0; k < NSIG / 4; ++k) {
      float4 wv = wrow[k];
      float4 hv = *(const float4*)&lds_h[k * 4];
      acc = fmaf(hv.x, wv.x, acc);
      acc = fmaf(hv.y, wv.y, acc);
      acc = fmaf(hv.z, wv.z, acc);
      acc = fmaf(hv.w, wv.w, acc);
    }
    out[b * NSIG + j] = acc;
  }
}

extern "C" void kernel_launch(void* const* d_in, const int* in_sizes, int n_in,
                              void* d_out, int out_size, void* d_ws, size_t ws_size,
                              hipStream_t stream) {
  const int*   ids = (const int*)d_in[0];
  const float* emb = (const float*)d_in[1];
  const float* pw  = (const float*)d_in[2];
  const float* pb  = (const float*)d_in[3];
  float*       out = (float*)d_out;

  rin_scan_kernel<<<dim3(BATCH), dim3(256), 0, stream>>>(ids, emb, pw, pb, out);
}

// Round 4
// 173.185 us; speedup vs baseline: 2.3751x; 1.0688x over previous
//
#include <hip/hip_runtime.h>

#define D_MODEL 64
#define SEQ     4096
#define BATCH   256
#define NSIG    128
#define CSTEP   64
#define NCHUNK  (SEQ / CSTEP)   // 64

constexpr float PHI_F     = 1.61803398874989484820f;
constexpr float TWO_PI_F  = 6.28318530717958647692f;
constexpr float INV2PI_F  = 0.15915494309189533577f;
constexpr float SCALE_F   = 4096.0f * 0.15915494309189533577f;  // 4096 / 2pi
constexpr float INV_LUT_F = 1.0f / 4096.0f;

// One block (256 threads = 4 waves) per batch element.
// wave 0: serial 4096-step scan (lane = model dim d), chain-latency-bound.
// waves 1-3: loaders — gather emb rows, pre-transform to (r4, c4) pairs,
// stage into a TRIPLE-buffered LDS ring TWO chunks ahead, so the compute
// wave can prefetch across chunk boundaries and never stalls on LDS.
__global__ __launch_bounds__(256, 1)
void rin_scan_kernel(const int* __restrict__ ids,
                     const float* __restrict__ emb,   // (50257, 128) f32
                     const float* __restrict__ pw,    // (128, 128) f32
                     const float* __restrict__ pb,    // (128,) f32
                     float* __restrict__ out)         // (256, 128) f32
{
  __shared__ float ring[3][CSTEP][2 * D_MODEL];      // 96 KB: [slot][step][2*lane + {r4,c4}]
  __shared__ float lds_h[2 * D_MODEL];

  const int tid  = threadIdx.x;
  const int wave = tid >> 6;
  const int lane = tid & 63;
  const int b    = blockIdx.x;

  float hr = 0.0f, hi = 0.0f;

  // ---- loader: stage chunk c into ring slot s (waves 1-3) ----
  // wave w handles steps i = 3k + (w-1), k = 0..21 (clamped dup at the end).
  auto stage = [&](int c, int s) {
    float wv[22], bv[22];
    #pragma unroll
    for (int k = 0; k < 22; ++k) {
      int i = 3 * k + (wave - 1); i = (i < CSTEP) ? i : (CSTEP - 1);
      int t = c * CSTEP + i;
      int id = ids[b * SEQ + t];                      // wave-uniform
      const float* row = emb + (size_t)id * (2 * D_MODEL);
      wv[k] = row[lane];
      bv[k] = row[D_MODEL + lane];
    }
    #pragma unroll
    for (int k = 0; k < 22; ++k) {
      int i = 3 * k + (wave - 1); i = (i < CSTEP) ? i : (CSTEP - 1);
      int t = c * CSTEP + i;
      // t_phi, bit-identical to prior rounds
      float pf  = (float)t * PHI_F;
      float n   = floorf(pf * INV2PI_F);
      float tp  = fmaf(-n, TWO_PI_F, pf);             // fmod(t*PHI, 2pi)
      float tp4 = tp * SCALE_F;
      float r4 = __builtin_amdgcn_rcpf(1.0f + fabsf(wv[k])) * SCALE_F;
      float c4 = fmaf(bv[k], SCALE_F, tp4);
      *(float2*)&ring[s][i][2 * lane] = make_float2(r4, c4);
    }
  };

  // ---- compute helpers (wave 0) ----
  auto prefetch8 = [&](const float* base, int g, float2* dst) {
    #pragma unroll
    for (int u = 0; u < 8; ++u)
      dst[u] = *(const float2*)&base[(g * 8 + u) * (2 * D_MODEL) + 2 * lane];
  };
  auto step8 = [&](const float2* rc) {
    #pragma unroll
    for (int u = 0; u < 8; ++u) {
      float xr = fmaf(hr, rc[u].x, rc[u].y);          // theta_r in LUT bins
      float xi = fmaf(hi, rc[u].x, rc[u].y);
      float kr = floorf(xr);
      float ki = floorf(xi);
      float f  = (kr + ki) * INV_LUT_F;               // exact: int * 2^-12
      f = __builtin_amdgcn_fractf(f);                 // mod 1 -> revolutions
      hr = __builtin_amdgcn_cosf(f);                  // cos(qr+qi)
      hi = __builtin_amdgcn_sinf(f);                  // sin(qr+qi)
    }
  };

  // ---- pipeline fill: loaders stage chunks 0 and 1 ----
  if (wave > 0) { stage(0, 0); stage(1, 1); }
  __syncthreads();

  float2 A[8], B[8];
  if (wave == 0) prefetch8(&ring[0][0][0], 0, A);

  int s = 0;
  for (int c = 0; c < NCHUNK; ++c) {
    int sn = s + 1; sn = (sn == 3) ? 0 : sn;
    int s2 = sn + 1; s2 = (s2 == 3) ? 0 : s2;
    if (wave > 0) {
      if (c + 2 < NCHUNK) stage(c + 2, s2);
    } else {
      const float* cur = &ring[s][0][0];
      const float* nxt = &ring[sn][0][0];
      prefetch8(cur, 1, B); step8(A);   // g0
      prefetch8(cur, 2, A); step8(B);   // g1
      prefetch8(cur, 3, B); step8(A);   // g2
      prefetch8(cur, 4, A); step8(B);   // g3
      prefetch8(cur, 5, B); step8(A);   // g4
      prefetch8(cur, 6, A); step8(B);   // g5
      prefetch8(cur, 7, B); step8(A);   // g6
      prefetch8(nxt, 0, A); step8(B);   // g7, cross-chunk prefetch
    }
    __syncthreads();
    s = sn;
  }

  // ---- projection: out[b, j] = sum_k h[k] * pw[j, k] + pb[j] ----
  if (wave == 0) {
    lds_h[lane] = hr;
    lds_h[D_MODEL + lane] = hi;
  }
  __syncthreads();
  if (tid < NSIG) {
    int j = tid;
    const float4* wrow = (const float4*)(pw + j * NSIG);
    float acc = pb[j];
    #pragma unroll
    for (int k = 0; k < NSIG / 4; ++k) {
      float4 wv = wrow[k];
      float4 hv = *(const float4*)&lds_h[k * 4];
      acc = fmaf(hv.x, wv.x, acc);
      acc = fmaf(hv.y, wv.y, acc);
      acc = fmaf(hv.z, wv.z, acc);
      acc = fmaf(hv.w, wv.w, acc);
    }
    out[b * NSIG + j] = acc;
  }
}

extern "C" void kernel_launch(void* const* d_in, const int* in_sizes, int n_in,
                              void* d_out, int out_size, void* d_ws, size_t ws_size,
                              hipStream_t stream) {
  const int*   ids = (const int*)d_in[0];
  const float* emb = (const float*)d_in[1];
  const float* pw  = (const float*)d_in[2];
  const float* pb  = (const float*)d_in[3];
  float*       out = (float*)d_out;

  rin_scan_kernel<<<dim3(BATCH), dim3(256), 0, stream>>>(ids, emb, pw, pb, out);
}

// Round 5
// 170.932 us; speedup vs baseline: 2.4065x; 1.0132x over previous
//
#include <hip/hip_runtime.h>

#define D_MODEL 64
#define SEQ     4096
#define BATCH   256
#define NSIG    128
#define CSTEP   64
#define NCHUNK  (SEQ / CSTEP)   // 64
#define NGRP    (SEQ / 8)       // 512 groups of 8 steps

constexpr float PHI_F     = 1.61803398874989484820f;
constexpr float TWO_PI_F  = 6.28318530717958647692f;
constexpr float INV2PI_F  = 0.15915494309189533577f;
constexpr float SCALE_F   = 4096.0f * 0.15915494309189533577f;  // 4096 / 2pi
constexpr float INV_LUT_F = 1.0f / 4096.0f;

// One block (256 threads = 4 waves) per batch element.
// wave 0: serial 4096-step scan (lane = model dim d), chain-latency-bound.
//   Register FIFO of 4 group-buffers, prefetch distance = 2 groups, with
//   consume-BEFORE-prefetch ordering so any lgkmcnt drain only sees loads
//   >= 8 steps (~450 cyc) old -> LDS latency fully hidden.
// waves 1-3: loaders — gather emb rows, pre-transform to (r4, c4) pairs,
//   stage into a triple-buffered LDS ring TWO chunks ahead.
__global__ __launch_bounds__(256, 1)
void rin_scan_kernel(const int* __restrict__ ids,
                     const float* __restrict__ emb,   // (50257, 128) f32
                     const float* __restrict__ pw,    // (128, 128) f32
                     const float* __restrict__ pb,    // (128,) f32
                     float* __restrict__ out)         // (256, 128) f32
{
  __shared__ float ring[3][CSTEP][2 * D_MODEL];      // 96 KB: [slot][step][2*lane + {r4,c4}]
  __shared__ float lds_h[2 * D_MODEL];

  const int tid  = threadIdx.x;
  const int wave = tid >> 6;
  const int lane = tid & 63;
  const int b    = blockIdx.x;

  float hr = 0.0f, hi = 0.0f;

  // ---- loader: stage chunk c into ring slot s (waves 1-3) ----
  auto stage = [&](int c, int s) {
    float wv[22], bv[22];
    #pragma unroll
    for (int k = 0; k < 22; ++k) {
      int i = 3 * k + (wave - 1); i = (i < CSTEP) ? i : (CSTEP - 1);
      int t = c * CSTEP + i;
      int id = ids[b * SEQ + t];                      // wave-uniform
      const float* row = emb + (size_t)id * (2 * D_MODEL);
      wv[k] = row[lane];
      bv[k] = row[D_MODEL + lane];
    }
    #pragma unroll
    for (int k = 0; k < 22; ++k) {
      int i = 3 * k + (wave - 1); i = (i < CSTEP) ? i : (CSTEP - 1);
      int t = c * CSTEP + i;
      float pf  = (float)t * PHI_F;
      float n   = floorf(pf * INV2PI_F);
      float tp  = fmaf(-n, TWO_PI_F, pf);             // fmod(t*PHI, 2pi)
      float tp4 = tp * SCALE_F;
      float r4 = __builtin_amdgcn_rcpf(1.0f + fabsf(wv[k])) * SCALE_F;
      float c4 = fmaf(bv[k], SCALE_F, tp4);
      *(float2*)&ring[s][i][2 * lane] = make_float2(r4, c4);
    }
  };

  // ---- compute helpers (wave 0); g = global group index 0..NGRP-1 ----
  auto P = [&](int g, float2* dst) {
    int gg = (g < NGRP) ? g : (NGRP - 1);
    const float* base = &ring[(gg >> 3) % 3][(gg & 7) * 8][0];
    #pragma unroll
    for (int u = 0; u < 8; ++u)
      dst[u] = *(const float2*)&base[u * (2 * D_MODEL) + 2 * lane];
  };
  auto S = [&](const float2* rc) {
    #pragma unroll
    for (int u = 0; u < 8; ++u) {
      float xr = fmaf(hr, rc[u].x, rc[u].y);          // theta_r in LUT bins
      float xi = fmaf(hi, rc[u].x, rc[u].y);
      float kr = floorf(xr);
      float ki = floorf(xi);
      float f  = (kr + ki) * INV_LUT_F;               // revolutions, in [-0.4, 3.1]
      hr = __builtin_amdgcn_cosf(f);                  // HW range reduction covers this
      hi = __builtin_amdgcn_sinf(f);
    }
  };

  // ---- pipeline fill: loaders stage chunks 0 and 1 ----
  if (wave > 0) { stage(0, 0); stage(1, 1); }
  __syncthreads();

  float2 F0[8], F1[8], F2[8], F3[8];
  if (wave == 0) { P(0, F0); P(1, F1); }

  for (int c = 0; c < NCHUNK; ++c) {
    if (wave > 0) {
      if (c + 2 < NCHUNK) stage(c + 2, (c + 2) % 3);
    } else {
      const int g0 = c * 8;
      // consume group g (buffer g&3), THEN prefetch g+2 into buffer (g+2)&3.
      S(F0); P(g0 + 2, F2);
      S(F1); P(g0 + 3, F3);
      S(F2); P(g0 + 4, F0);
      S(F3); P(g0 + 5, F1);
      S(F0); P(g0 + 6, F2);
      S(F1); P(g0 + 7, F3);
      S(F2); P(g0 + 8, F0);
      S(F3); P(g0 + 9, F1);
    }
    __syncthreads();
  }

  // ---- projection: out[b, j] = sum_k h[k] * pw[j, k] + pb[j] ----
  if (wave == 0) {
    lds_h[lane] = hr;
    lds_h[D_MODEL + lane] = hi;
  }
  __syncthreads();
  if (tid < NSIG) {
    int j = tid;
    const float4* wrow = (const float4*)(pw + j * NSIG);
    float acc = pb[j];
    #pragma unroll
    for (int k = 0; k < NSIG / 4; ++k) {
      float4 wv = wrow[k];
      float4 hv = *(const float4*)&lds_h[k * 4];
      acc = fmaf(hv.x, wv.x, acc);
      acc = fmaf(hv.y, wv.y, acc);
      acc = fmaf(hv.z, wv.z, acc);
      acc = fmaf(hv.w, wv.w, acc);
    }
    out[b * NSIG + j] = acc;
  }
}

extern "C" void kernel_launch(void* const* d_in, const int* in_sizes, int n_in,
                              void* d_out, int out_size, void* d_ws, size_t ws_size,
                              hipStream_t stream) {
  const int*   ids = (const int*)d_in[0];
  const float* emb = (const float*)d_in[1];
  const float* pw  = (const float*)d_in[2];
  const float* pb  = (const float*)d_in[3];
  float*       out = (float*)d_out;

  rin_scan_kernel<<<dim3(BATCH), dim3(256), 0, stream>>>(ids, emb, pw, pb, out);
}